// Round 2
// baseline (411.711 us; speedup 1.0000x reference)
//
#include <hip/hip_runtime.h>

typedef float    f32x4 __attribute__((ext_vector_type(4)));
typedef __bf16   bf16x8 __attribute__((ext_vector_type(8)));
typedef _Float16 f16x4 __attribute__((ext_vector_type(4)));

static __device__ __forceinline__ unsigned short f2bf(float f) {
  union { float f; unsigned int u; } a; a.f = f;
  unsigned int r = (a.u + 0x7FFFu + ((a.u >> 16) & 1u)) >> 16;
  return (unsigned short)r;
}

#define QSCALE 0.24253562503633297f  // 1/sqrt(17)

// Weights -> bf16 MFMA fragments (serves as A-frag for swapped Q/K proj and
// B-frag for normal V proj; identical lane mapping).
// wf[((w*32 + n*4 + kk)*512) + p*8 + i] = W_w[kk*32+(p>>4)*8+i][n*16+(p&15)]
// (w==0 scaled by QSCALE)
__global__ void prep_weights(const float* __restrict__ Wq, const float* __restrict__ Wk,
                             const float* __restrict__ Wv, unsigned short* __restrict__ wf) {
  int idx = blockIdx.x * 256 + threadIdx.x;
  if (idx >= 3 * 8 * 4 * 64 * 8) return;
  int i  = idx & 7;
  int p  = (idx >> 3) & 63;
  int kk = (idx >> 9) & 3;
  int n  = (idx >> 11) & 7;
  int w  = idx >> 14;
  const float* W = (w == 0) ? Wq : ((w == 1) ? Wk : Wv);
  float val = W[(kk * 32 + (p >> 4) * 8 + i) * 128 + n * 16 + (p & 15)];
  if (w == 0) val *= QSCALE;
  wf[idx] = f2bf(val);
}

// posW[w][t][d] = sum_k pos[t][k]*W_w[k][d]  (w==0 scaled), stored per-lane as
// the f32 accumulator-init fragment for head h:
//  w<2 (swapped):  acc[r] = posW[t=l&15][d=h*16+(l>>4)*4+r]
//  w==2 (normal):  acc[r] = posW[t=(l>>4)*4+r][d=h*16+(l&15)]
// pw[((w*8+h)*64+l)*4 + r]
__global__ void prep_posw(const float* __restrict__ pos, const float* __restrict__ Wq,
                          const float* __restrict__ Wk, const float* __restrict__ Wv,
                          float* __restrict__ pw) {
  int idx = blockIdx.x * 256 + threadIdx.x;
  if (idx >= 3 * 8 * 64 * 4) return;
  int r = idx & 3;
  int l = (idx >> 2) & 63;
  int h = (idx >> 8) & 7;
  int w = idx >> 11;
  const float* W = (w == 0) ? Wq : ((w == 1) ? Wk : Wv);
  int t, d;
  if (w < 2) { t = l & 15;            d = h * 16 + (l >> 4) * 4 + r; }
  else       { t = (l >> 4) * 4 + r;  d = h * 16 + (l & 15); }
  float s = 0.f;
  for (int k = 0; k < 128; ++k) s += pos[t * 128 + k] * W[k * 128 + d];
  if (w == 0) s *= QSCALE;
  pw[idx] = s;
}

__global__ __launch_bounds__(512, 4) void attn_main(
    const float* __restrict__ xin, const float* __restrict__ pos,
    const unsigned short* __restrict__ wfrag, const float* __restrict__ pw,
    float* __restrict__ out, int B) {
  const int tid  = threadIdx.x;
  const int wid  = tid >> 6;   // wave = head 0..7
  const int l    = tid & 63;
  const int frow = l & 15;
  const int fkq  = l >> 4;
  const int trow0 = fkq * 4;

  // weight fragments for this head: 3 W x 4 K-steps = 48 VGPRs
  bf16x8 wf[3][4];
#pragma unroll
  for (int w = 0; w < 3; ++w)
#pragma unroll
    for (int kk = 0; kk < 4; ++kk)
      wf[w][kk] = *(const bf16x8*)(wfrag + ((w * 32 + wid * 4 + kk) * 512) + l * 8);

  // pos*W accumulator-init fragments (12 VGPRs)
  f32x4 posw[3];
#pragma unroll
  for (int w = 0; w < 3; ++w)
    posw[w] = *(const f32x4*)(pw + ((w * 8 + wid) * 64 + l) * 4);

  // pos slice for this wave's pass-through quarter (4 VGPRs)
  const int ptcol = (wid >> 1) * 32 + fkq * 8 + (wid & 1) * 4;
  const f32x4 posp = *(const f32x4*)(pos + frow * 128 + ptcol);

  const float LOG2E = 1.4426950408889634f;
  const f32x4 zero4 = {0.f, 0.f, 0.f, 0.f};

  for (int b = blockIdx.x; b < B; b += gridDim.x) {
    const float* xb = xin + (size_t)b * 2048;
    float* ob = out + (size_t)b * 4096;

    // ---- load x row fragments (B-frag layout), keep pass-through slice ----
    bf16x8 xf[4];
    f32x4 pt;
#pragma unroll
    for (int kk = 0; kk < 4; ++kk) {
      const float* xp = xb + frow * 128 + kk * 32 + fkq * 8;
      f32x4 a0 = *(const f32x4*)xp;
      f32x4 a1 = *(const f32x4*)(xp + 4);
      if (kk == (wid >> 1)) pt = ((wid & 1) ? a1 : a0) + posp;
      xf[kk][0] = (__bf16)a0.x; xf[kk][1] = (__bf16)a0.y;
      xf[kk][2] = (__bf16)a0.z; xf[kk][3] = (__bf16)a0.w;
      xf[kk][4] = (__bf16)a1.x; xf[kk][5] = (__bf16)a1.y;
      xf[kk][6] = (__bf16)a1.z; xf[kk][7] = (__bf16)a1.w;
    }
    // pass-through store: out[:, :, 128:256] = x + pos
    *(f32x4*)(ob + frow * 256 + 128 + ptcol) = pt;

    // ---- projections: Q,K swapped (W as A -> Q^T/K^T), V normal ----
    f32x4 qa = posw[0], ka = posw[1], va = posw[2];
#pragma unroll
    for (int kk = 0; kk < 4; ++kk) {
      qa = __builtin_amdgcn_mfma_f32_16x16x32_bf16(wf[0][kk], xf[kk], qa, 0, 0, 0);
      ka = __builtin_amdgcn_mfma_f32_16x16x32_bf16(wf[1][kk], xf[kk], ka, 0, 0, 0);
      va = __builtin_amdgcn_mfma_f32_16x16x32_bf16(xf[kk], wf[2][kk], va, 0, 0, 0);
    }
    f16x4 qh, kh, vh;
#pragma unroll
    for (int r = 0; r < 4; ++r) {
      qh[r] = (_Float16)qa[r];
      kh[r] = (_Float16)ka[r];
      vh[r] = (_Float16)va[r];
    }

    // ---- scores^T = K · Q^T  (lane holds S^T[s=trow0+r][t=frow]) ----
    f32x4 st = __builtin_amdgcn_mfma_f32_16x16x16f16(kh, qh, zero4, 0, 0, 0);
    float sv0 = (trow0 + 0 <= frow) ? st[0] : -1e30f;
    float sv1 = (trow0 + 1 <= frow) ? st[1] : -1e30f;
    float sv2 = (trow0 + 2 <= frow) ? st[2] : -1e30f;
    float sv3 = (trow0 + 3 <= frow) ? st[3] : -1e30f;
    float m = fmaxf(fmaxf(sv0, sv1), fmaxf(sv2, sv3));
    m = fmaxf(m, __shfl_xor(m, 16));
    m = fmaxf(m, __shfl_xor(m, 32));
    float p0 = exp2f((sv0 - m) * LOG2E);
    float p1 = exp2f((sv1 - m) * LOG2E);
    float p2 = exp2f((sv2 - m) * LOG2E);
    float p3 = exp2f((sv3 - m) * LOG2E);
    float ssum = (p0 + p1) + (p2 + p3);
    ssum += __shfl_xor(ssum, 16);
    ssum += __shfl_xor(ssum, 32);
    float inv = __builtin_amdgcn_rcpf(ssum);
    f16x4 ah;
    ah[0] = (_Float16)(p0 * inv);
    ah[1] = (_Float16)(p1 * inv);
    ah[2] = (_Float16)(p2 * inv);
    ah[3] = (_Float16)(p3 * inv);

    // ---- o^T = V^T · attn^T  (lane holds o[t=frow][d=trow0+r]) ----
    f32x4 ot = __builtin_amdgcn_mfma_f32_16x16x16f16(vh, ah, zero4, 0, 0, 0);
    f32x4 ov;
#pragma unroll
    for (int r = 0; r < 4; ++r) {
      float x = ot[r];
      ov[r] = x > 0.f ? 2.f * x : x;
    }
    *(f32x4*)(ob + frow * 256 + wid * 16 + trow0) = ov;
  }
}

extern "C" void kernel_launch(void* const* d_in, const int* in_sizes, int n_in,
                              void* d_out, int out_size, void* d_ws, size_t ws_size,
                              hipStream_t stream) {
  (void)n_in; (void)out_size; (void)ws_size;
  const float* xin = (const float*)d_in[0];
  const float* pos = (const float*)d_in[1];
  const float* Wq  = (const float*)d_in[2];
  const float* Wk  = (const float*)d_in[3];
  const float* Wv  = (const float*)d_in[4];
  float* out = (float*)d_out;
  unsigned short* wf = (unsigned short*)d_ws;            // 96 KiB
  float* pw = (float*)((char*)d_ws + 3 * 8 * 4 * 64 * 8 * sizeof(unsigned short));  // 24 KiB
  int B = in_sizes[0] / 2048;

  hipLaunchKernelGGL(prep_weights, dim3(192), dim3(256), 0, stream, Wq, Wk, Wv, wf);
  hipLaunchKernelGGL(prep_posw, dim3(24), dim3(256), 0, stream, pos, Wq, Wk, Wv, wf ? pw : pw);
  hipLaunchKernelGGL(attn_main, dim3(4096), dim3(512), 0, stream, xin, pos, wf, pw, out, B);
}

// Round 3
// 383.300 us; speedup vs baseline: 1.0741x; 1.0741x over previous
//
#include <hip/hip_runtime.h>

typedef float    f32x4 __attribute__((ext_vector_type(4)));
typedef __bf16   bf16x8 __attribute__((ext_vector_type(8)));
typedef _Float16 f16x4 __attribute__((ext_vector_type(4)));

static __device__ __forceinline__ unsigned short f2bf(float f) {
  union { float f; unsigned int u; } a; a.f = f;
  unsigned int r = (a.u + 0x7FFFu + ((a.u >> 16) & 1u)) >> 16;
  return (unsigned short)r;
}

#define QSCALE 0.24253562503633297f  // 1/sqrt(17)

// Weights -> bf16 MFMA fragments (A-frag for swapped Q/K proj, B-frag for
// normal V proj; identical lane mapping).
// wf[((w*32 + n*4 + kk)*512) + p*8 + i] = W_w[kk*32+(p>>4)*8+i][n*16+(p&15)]
// (w==0 scaled by QSCALE)
__global__ void prep_weights(const float* __restrict__ Wq, const float* __restrict__ Wk,
                             const float* __restrict__ Wv, unsigned short* __restrict__ wf) {
  int idx = blockIdx.x * 256 + threadIdx.x;
  if (idx >= 3 * 8 * 4 * 64 * 8) return;
  int i  = idx & 7;
  int p  = (idx >> 3) & 63;
  int kk = (idx >> 9) & 3;
  int n  = (idx >> 11) & 7;
  int w  = idx >> 14;
  const float* W = (w == 0) ? Wq : ((w == 1) ? Wk : Wv);
  float val = W[(kk * 32 + (p >> 4) * 8 + i) * 128 + n * 16 + (p & 15)];
  if (w == 0) val *= QSCALE;
  wf[idx] = f2bf(val);
}

// posW[w][t][d] = sum_k pos[t][k]*W_w[k][d]  (w==0 scaled), per-lane f32
// accumulator-init fragment for head h:
//  w<2 (swapped):  acc[r] = posW[t=l&15][d=h*16+(l>>4)*4+r]
//  w==2 (normal):  acc[r] = posW[t=(l>>4)*4+r][d=h*16+(l&15)]
__global__ void prep_posw(const float* __restrict__ pos, const float* __restrict__ Wq,
                          const float* __restrict__ Wk, const float* __restrict__ Wv,
                          float* __restrict__ pw) {
  int idx = blockIdx.x * 256 + threadIdx.x;
  if (idx >= 3 * 8 * 64 * 4) return;
  int r = idx & 3;
  int l = (idx >> 2) & 63;
  int h = (idx >> 8) & 7;
  int w = idx >> 11;
  const float* W = (w == 0) ? Wq : ((w == 1) ? Wk : Wv);
  int t, d;
  if (w < 2) { t = l & 15;            d = h * 16 + (l >> 4) * 4 + r; }
  else       { t = (l >> 4) * 4 + r;  d = h * 16 + (l & 15); }
  float s = 0.f;
  for (int k = 0; k < 128; ++k) s += pos[t * 128 + k] * W[k * 128 + d];
  if (w == 0) s *= QSCALE;
  pw[idx] = s;
}

__global__ void __launch_bounds__(512)
__attribute__((amdgpu_waves_per_eu(4, 4)))
attn_main(const float* __restrict__ xin, const float* __restrict__ pos,
          const unsigned short* __restrict__ wfrag, const float* __restrict__ pw,
          float* __restrict__ out, int B) {
  const int tid  = threadIdx.x;
  const int wid  = tid >> 6;   // wave = head 0..7
  const int l    = tid & 63;
  const int frow = l & 15;
  const int fkq  = l >> 4;
  const int trow0 = fkq * 4;

  // weight fragments for this head: 3 W x 4 K-steps = 48 VGPRs
  bf16x8 wf[3][4];
#pragma unroll
  for (int w = 0; w < 3; ++w)
#pragma unroll
    for (int kk = 0; kk < 4; ++kk)
      wf[w][kk] = *(const bf16x8*)(wfrag + ((w * 32 + wid * 4 + kk) * 512) + l * 8);

  // pos*W accumulator-init fragments (12 VGPRs)
  f32x4 posw[3];
#pragma unroll
  for (int w = 0; w < 3; ++w)
    posw[w] = *(const f32x4*)(pw + ((w * 8 + wid) * 64 + l) * 4);

  // pos slice for this wave's pass-through quarter (4 VGPRs)
  const int ptcol = (wid >> 1) * 32 + fkq * 8 + (wid & 1) * 4;
  f32x4 posp = *(const f32x4*)(pos + frow * 128 + ptcol);

  // Pin all loop-invariants as asm-defined: cannot be rematerialized/spilled
  // back to per-iteration loads by the register allocator.
#pragma unroll
  for (int w = 0; w < 3; ++w) {
#pragma unroll
    for (int kk = 0; kk < 4; ++kk) asm volatile("" : "+v"(wf[w][kk]));
    asm volatile("" : "+v"(posw[w]));
  }
  asm volatile("" : "+v"(posp));

  const float LOG2E = 1.4426950408889634f;
  const f32x4 zero4 = {0.f, 0.f, 0.f, 0.f};

  for (int b = blockIdx.x; b < B; b += gridDim.x) {
    const float* xb = xin + (size_t)b * 2048;
    float* ob = out + (size_t)b * 4096;

    // ---- load x row fragments (B-frag layout), keep pass-through slice ----
    bf16x8 xf[4];
    f32x4 pt;
#pragma unroll
    for (int kk = 0; kk < 4; ++kk) {
      const float* xp = xb + frow * 128 + kk * 32 + fkq * 8;
      f32x4 a0 = *(const f32x4*)xp;
      f32x4 a1 = *(const f32x4*)(xp + 4);
      if (kk == (wid >> 1)) pt = ((wid & 1) ? a1 : a0) + posp;
      xf[kk][0] = (__bf16)a0.x; xf[kk][1] = (__bf16)a0.y;
      xf[kk][2] = (__bf16)a0.z; xf[kk][3] = (__bf16)a0.w;
      xf[kk][4] = (__bf16)a1.x; xf[kk][5] = (__bf16)a1.y;
      xf[kk][6] = (__bf16)a1.z; xf[kk][7] = (__bf16)a1.w;
    }
    // pass-through store: out[:, :, 128:256] = x + pos
    *(f32x4*)(ob + frow * 256 + 128 + ptcol) = pt;

    // ---- projections: Q,K swapped (W as A -> Q^T/K^T), V normal ----
    f32x4 qa = posw[0], ka = posw[1], va = posw[2];
#pragma unroll
    for (int kk = 0; kk < 4; ++kk) {
      qa = __builtin_amdgcn_mfma_f32_16x16x32_bf16(wf[0][kk], xf[kk], qa, 0, 0, 0);
      ka = __builtin_amdgcn_mfma_f32_16x16x32_bf16(wf[1][kk], xf[kk], ka, 0, 0, 0);
      va = __builtin_amdgcn_mfma_f32_16x16x32_bf16(xf[kk], wf[2][kk], va, 0, 0, 0);
    }
    f16x4 qh, kh, vh;
#pragma unroll
    for (int r = 0; r < 4; ++r) {
      qh[r] = (_Float16)qa[r];
      kh[r] = (_Float16)ka[r];
      vh[r] = (_Float16)va[r];
    }

    // ---- scores^T = K · Q^T (lane holds S^T[s=trow0+r][t=frow]) ----
    // Softmax WITHOUT max-subtraction (shift-invariant; |s| small, exp2f safe).
    f32x4 st = __builtin_amdgcn_mfma_f32_16x16x16f16(kh, qh, zero4, 0, 0, 0);
    float p0 = (trow0 + 0 <= frow) ? exp2f(st[0] * LOG2E) : 0.f;
    float p1 = (trow0 + 1 <= frow) ? exp2f(st[1] * LOG2E) : 0.f;
    float p2 = (trow0 + 2 <= frow) ? exp2f(st[2] * LOG2E) : 0.f;
    float p3 = (trow0 + 3 <= frow) ? exp2f(st[3] * LOG2E) : 0.f;
    float ssum = (p0 + p1) + (p2 + p3);
    ssum += __shfl_xor(ssum, 16);
    ssum += __shfl_xor(ssum, 32);
    float inv = __builtin_amdgcn_rcpf(ssum);
    f16x4 ah;
    ah[0] = (_Float16)(p0 * inv);
    ah[1] = (_Float16)(p1 * inv);
    ah[2] = (_Float16)(p2 * inv);
    ah[3] = (_Float16)(p3 * inv);

    // ---- o^T = V^T · attn^T (lane holds o[t=frow][d=trow0+r]) ----
    f32x4 ot = __builtin_amdgcn_mfma_f32_16x16x16f16(vh, ah, zero4, 0, 0, 0);
    f32x4 ov;
#pragma unroll
    for (int r = 0; r < 4; ++r) {
      float x = ot[r];
      ov[r] = x > 0.f ? 2.f * x : x;
    }
    *(f32x4*)(ob + frow * 256 + wid * 16 + trow0) = ov;
  }
}

extern "C" void kernel_launch(void* const* d_in, const int* in_sizes, int n_in,
                              void* d_out, int out_size, void* d_ws, size_t ws_size,
                              hipStream_t stream) {
  (void)n_in; (void)out_size; (void)ws_size;
  const float* xin = (const float*)d_in[0];
  const float* pos = (const float*)d_in[1];
  const float* Wq  = (const float*)d_in[2];
  const float* Wk  = (const float*)d_in[3];
  const float* Wv  = (const float*)d_in[4];
  float* out = (float*)d_out;
  unsigned short* wf = (unsigned short*)d_ws;            // 96 KiB
  float* pw = (float*)((char*)d_ws + 3 * 8 * 4 * 64 * 8 * sizeof(unsigned short));  // 24 KiB
  int B = in_sizes[0] / 2048;

  hipLaunchKernelGGL(prep_weights, dim3(192), dim3(256), 0, stream, Wq, Wk, Wv, wf);
  hipLaunchKernelGGL(prep_posw, dim3(24), dim3(256), 0, stream, pos, Wq, Wk, Wv, pw);
  hipLaunchKernelGGL(attn_main, dim3(4096), dim3(512), 0, stream, xin, pos, wf, pw, out, B);
}